// Round 7
// baseline (991.157 us; speedup 1.0000x reference)
//
#include <hip/hip_runtime.h>
#include <hip/hip_bf16.h>

#define N_NODE  100000
#define N_EDGE  800000
#define FEATD   128
#define NTILES  3125          /* 800000 / 256 edges per block-tile */
#define GRID    256
#define NWAVES  (GRID * 16)      /* 4096 */
#define NTHREADS (GRID * 1024)   /* 262144 */

typedef float  f32x4 __attribute__((ext_vector_type(4)));
typedef short  s16x8 __attribute__((ext_vector_type(8)));

static __device__ __forceinline__ float bf2f(ushort h) {
    union { uint u; float f; } v; v.u = ((uint)h) << 16; return v.f;
}
static __device__ __forceinline__ ushort f2bf(float f) {
    union { float f; uint u; } v; v.f = f;
    uint u = v.u;
    u = u + 0x7FFFu + ((u >> 16) & 1u);   // RNE
    return (ushort)(u >> 16);
}
static __device__ __forceinline__ uint cvtpk(float lo, float hi) {
    uint r;
    asm("v_cvt_pk_bf16_f32 %0, %1, %2" : "=v"(r) : "v"(lo), "v"(hi));
    return r;
}
static __device__ __forceinline__ uint prodpk(uint ua, uint ub) {
    union { uint u; float f; } al, ah, bl, bh;
    al.u = ua << 16; ah.u = ua & 0xFFFF0000u;
    bl.u = ub << 16; bh.u = ub & 0xFFFF0000u;
    return cvtpk(al.f * bl.f, ah.f * bh.f);
}
static __device__ __forceinline__ float lof(uint u) {
    union { uint u; float f; } v; v.u = u << 16; return v.f;
}
static __device__ __forceinline__ float hif(uint u) {
    union { uint u; float f; } v; v.u = u & 0xFFFF0000u; return v.f;
}

// LDS / weight-image layout (bytes), weights XOR-swizzled: byte ^= (row&7)<<4
#define LOFF_WL   0           /* 128 rows x 256B bf16 */
#define LOFF_WR   32768
#define LOFF_W1   65536       /* 64 rows x 256B */
#define LOFF_W2   81920       /* 32 rows x 128B */
#define LOFF_BL   86016
#define LOFF_B1   86528
#define LOFF_B2   86784
#define LOFF_W3   86912       /* 64 f32: W3[2][32] */
#define LOFF_B3   87168
#define IMG_BYTES 87184
#define LOFF_ABUF 87184       /* 16 waves x 4096B transpose buf; scan scratch early */
#define LDS_TOTAL (LOFF_ABUF + 16 * 4096)   /* 152720 */

// ---------------- K_pre1: n_fea f32->bf16 + dst histogram + weight image ----
__global__ void k_pre1(const float* __restrict__ rna, const float* __restrict__ prot,
                       ushort* __restrict__ nfbf, const int* __restrict__ ei,
                       int* __restrict__ cnt_i,
                       const float* __restrict__ Wl, const float* __restrict__ Wr,
                       const float* __restrict__ W1, const float* __restrict__ W2,
                       const float* __restrict__ bl, const float* __restrict__ b1,
                       const float* __restrict__ b2, const float* __restrict__ W3,
                       const float* __restrict__ b3, char* __restrict__ wimg) {
    int b = blockIdx.x;
    if (b < 12500) {
        int i = (b * 256 + threadIdx.x) * 4;
        const float* src = (i < 50000 * FEATD) ? (rna + i) : (prot + (i - 50000 * FEATD));
        float4 v = *(const float4*)src;
        ushort4 o;
        o.x = f2bf(v.x); o.y = f2bf(v.y); o.z = f2bf(v.z); o.w = f2bf(v.w);
        *(ushort4*)(nfbf + i) = o;
    } else if (b < 15625) {
        int e = (b - 12500) * 256 + threadIdx.x;
        atomicAdd(&cnt_i[ei[N_EDGE + e]], 1);
    } else if (b < 15667) {
        // weights -> swizzled bf16 image (42 blocks x 1024 elems)
        int base = (b - 15625) * 1024 + threadIdx.x * 4;
#pragma unroll
        for (int q = 0; q < 4; ++q) {
            int i = base + q;
            if (i < 16384) {
                int row = i >> 7, col = i & 127;
                *(ushort*)(wimg + LOFF_WL + row * 256 + ((2 * col) ^ ((row & 7) << 4))) = f2bf(Wl[i]);
            } else if (i < 32768) {
                int j = i - 16384, row = j >> 7, col = j & 127;
                *(ushort*)(wimg + LOFF_WR + row * 256 + ((2 * col) ^ ((row & 7) << 4))) = f2bf(Wr[j]);
            } else if (i < 40960) {
                int j = i - 32768, row = j >> 7, col = j & 127;
                *(ushort*)(wimg + LOFF_W1 + row * 256 + ((2 * col) ^ ((row & 7) << 4))) = f2bf(W1[j]);
            } else if (i < 43008) {
                int j = i - 40960, row = j >> 6, col = j & 63;
                *(ushort*)(wimg + LOFF_W2 + row * 128 + ((2 * col) ^ ((row & 7) << 4))) = f2bf(W2[j]);
            }
        }
    } else {
        // biases + W3/b3: 256-thread block, threads 0..65 do TWO writes
        int t = threadIdx.x;
        if (t < 128)      *(float*)(wimg + LOFF_BL + t * 4) = bl[t];
        else if (t < 192) *(float*)(wimg + LOFF_B1 + (t - 128) * 4) = b1[t - 128];
        else if (t < 224) *(float*)(wimg + LOFF_B2 + (t - 192) * 4) = b2[t - 192];
        if (t < 64)       *(float*)(wimg + LOFF_W3 + t * 4) = W3[t];
        else if (t < 66)  *(float*)(wimg + LOFF_B3 + (t - 64) * 4) = b3[t - 64];
    }
}

// ---------------- grid barrier helpers (256 co-resident blocks) --------------
static __device__ __forceinline__ void bar_arrive_wait(int* flag) {
    __threadfence();
    __syncthreads();
    if (threadIdx.x == 0) {
        __hip_atomic_fetch_add(flag, 1, __ATOMIC_RELEASE, __HIP_MEMORY_SCOPE_AGENT);
        while (__hip_atomic_load(flag, __ATOMIC_ACQUIRE, __HIP_MEMORY_SCOPE_AGENT) < GRID)
            __builtin_amdgcn_s_sleep(2);
    }
    __syncthreads();
    __threadfence();
}

// ---------------- K_mega: scan + xlow/fill/labels + agg + MLP ----------------
__global__ __launch_bounds__(1024, 4) void k_mega(
        const int* __restrict__ ei, const ushort* __restrict__ nfbf,
        ushort* __restrict__ xlow, ushort* __restrict__ meanbf,
        const int* __restrict__ cnt_i, int* __restrict__ offs,
        int* __restrict__ wptr, int* __restrict__ elist,
        int* __restrict__ bsum, int* __restrict__ flags,
        const char* __restrict__ wimg, float* __restrict__ out)
{
    extern __shared__ char smem[];
    const int tid = threadIdx.x;
    const int bid = blockIdx.x;

    // ---- stage pre-built weight image (straight copy) ----
    {
        const uint4* src = (const uint4*)wimg;
        uint4* dst = (uint4*)smem;
        for (int i = tid; i < IMG_BYTES / 16; i += 1024) dst[i] = src[i];
    }

    // ---- S1: per-block inclusive scan of a 391-wide chunk of cnt_i ----
    int* sc = (int*)(smem + LOFF_ABUF);          // 512 ints
    const int idx0 = bid * 391;
    if (tid < 512) sc[tid] = (tid < 391 && idx0 + tid < N_NODE) ? cnt_i[idx0 + tid] : 0;
    __syncthreads();
    for (int o = 1; o < 512; o <<= 1) {
        int v = (tid < 512 && tid >= o) ? sc[tid - o] : 0;
        __syncthreads();
        if (tid < 512) sc[tid] += v;
        __syncthreads();
    }
    if (tid == 0) bsum[bid] = sc[390];
    bar_arrive_wait(&flags[0]);

    // ---- S2/S3: every block scans the 256 block-sums; write offs/wptr ----
    int* sb = (int*)(smem + LOFF_ABUF + 2048);   // 256 ints
    if (tid < 256) sb[tid] = bsum[tid];
    __syncthreads();
    for (int o = 1; o < 256; o <<= 1) {
        int v = (tid < 256 && tid >= o) ? sb[tid - o] : 0;
        __syncthreads();
        if (tid < 256) sb[tid] += v;
        __syncthreads();
    }
    {
        int bbase = (bid == 0) ? 0 : sb[bid - 1];
        if (tid < 391 && idx0 + tid < N_NODE) {
            int excl = ((tid == 0) ? 0 : sc[tid - 1]) + bbase;
            offs[idx0 + tid] = excl;
            wptr[idx0 + tid] = excl;
        }
    }
    bar_arrive_wait(&flags[1]);

    const int w = tid >> 6, lane = tid & 63;
    const int gwave = bid * 16 + w;
    const int gtid  = bid * 1024 + tid;

    // ---- P0: xlow (2-row ILP) + CSR fill + labels ----
    for (int s = gwave; s < N_NODE; s += 2 * NWAVES) {
        int s2 = s + NWAVES;
        bool have2 = (s2 < N_NODE);
        int a0i = ei[s], d0i = ei[N_EDGE + s];
        int a1i = a0i, d1i = d0i;
        if (have2) { a1i = ei[s2]; d1i = ei[N_EDGE + s2]; }
        uint ua0 = *(const uint*)(nfbf + (size_t)a0i * FEATD + lane * 2);
        uint ub0 = *(const uint*)(nfbf + (size_t)d0i * FEATD + lane * 2);
        uint ua1 = *(const uint*)(nfbf + (size_t)a1i * FEATD + lane * 2);
        uint ub1 = *(const uint*)(nfbf + (size_t)d1i * FEATD + lane * 2);
        *(uint*)(xlow + (size_t)s * FEATD + lane * 2) = prodpk(ua0, ub0);
        if (have2) *(uint*)(xlow + (size_t)s2 * FEATD + lane * 2) = prodpk(ua1, ub1);
    }
    for (int e = gtid; e < N_EDGE; e += NTHREADS) {
        int d = ei[N_EDGE + e], s = ei[e];
        int pos = atomicAdd(&wptr[d], 1);
        elist[pos] = s;
    }
    if (gtid < N_EDGE / 4) {
        float val = (gtid * 4 < N_EDGE / 2) ? 1.0f : 0.0f;
        float4 v = { val, val, val, val };
        *(float4*)(out + 2 * (size_t)N_EDGE + gtid * 4) = v;
    }
    bar_arrive_wait(&flags[2]);

    // ---- P1: gather aggregation -> meanbf (4 gathers in flight) ----
    for (int n = gwave; n < N_NODE; n += NWAVES) {
        int c = cnt_i[n], base = offs[n];
        float A0 = 0.f, A1 = 0.f;
        for (int ch = 0; ch < c; ch += 64) {
            int m = min(64, c - ch);
            int ev = elist[base + ch + ((lane < m) ? lane : 0)];
            int k = 0;
            for (; k + 4 <= m; k += 4) {
                int s0 = __shfl(ev, k),     s1 = __shfl(ev, k + 1);
                int s2 = __shfl(ev, k + 2), s3 = __shfl(ev, k + 3);
                uint u0 = *(const uint*)(xlow + (size_t)s0 * FEATD + lane * 2);
                uint u1 = *(const uint*)(xlow + (size_t)s1 * FEATD + lane * 2);
                uint u2 = *(const uint*)(xlow + (size_t)s2 * FEATD + lane * 2);
                uint u3 = *(const uint*)(xlow + (size_t)s3 * FEATD + lane * 2);
                A0 += lof(u0) + lof(u1) + lof(u2) + lof(u3);
                A1 += hif(u0) + hif(u1) + hif(u2) + hif(u3);
            }
            for (; k < m; ++k) {
                int s0 = __shfl(ev, k);
                uint u = *(const uint*)(xlow + (size_t)s0 * FEATD + lane * 2);
                A0 += lof(u); A1 += hif(u);
            }
        }
        float scv = 1.0f / fmaxf((float)c, 1.0f);
        *(uint*)(meanbf + (size_t)n * FEATD + lane * 2) = cvtpk(A0 * scv, A1 * scv);
    }
    // arrive-only: high tiles don't need meanbf
    __threadfence();
    __syncthreads();
    if (tid == 0)
        __hip_atomic_fetch_add(&flags[3], 1, __ATOMIC_RELEASE, __HIP_MEMORY_SCOPE_AGENT);
    __syncthreads();

    // ---- P2: MLP tiles, high tiles first; spin on agg flag before low ----
    const int arow = lane & 15, agrp = lane >> 4;
    char* ab = smem + LOFF_ABUF + w * 4096;
    const float* W3s = (const float*)(smem + LOFF_W3);
    const float* B3s = (const float*)(smem + LOFF_B3);
    bool mean_ready = false;
    const int nj = (NTILES - 1 - bid) / GRID + 1;

    for (int j = nj - 1; j >= 0; --j) {
        const int tile = bid + j * GRID;
        const int eb = tile * 256 + w * 16;          // this wave's 16 edges
        const bool low = (eb < N_NODE);              // 16-aligned boundary: exact
        if (low && !mean_ready) {
            while (__hip_atomic_load(&flags[3], __ATOMIC_ACQUIRE, __HIP_MEMORY_SCOPE_AGENT) < GRID)
                __builtin_amdgcn_s_sleep(2);
            __threadfence();
            mean_ready = true;
        }

        // ---- build layer-1 A fragments directly in registers ----
        s16x8 ax[4], am[4];
        if (low) {
            const ushort* xr = xlow   + (size_t)(eb + arow) * FEATD + agrp * 8;
            const ushort* mr = meanbf + (size_t)(eb + arow) * FEATD + agrp * 8;
#pragma unroll
            for (int t = 0; t < 4; ++t) {
                ax[t] = *(const s16x8*)(xr + t * 32);
                am[t] = *(const s16x8*)(mr + t * 32);
            }
        } else {
            int e = eb + arow;
            int s = ei[e], d = ei[N_EDGE + e];
            const ushort* sr = nfbf + (size_t)s * FEATD + agrp * 8;
            const ushort* dr = nfbf + (size_t)d * FEATD + agrp * 8;
            s16x8 av[4], bv[4];
#pragma unroll
            for (int t = 0; t < 4; ++t) {
                av[t] = *(const s16x8*)(sr + t * 32);
                bv[t] = *(const s16x8*)(dr + t * 32);
            }
#pragma unroll
            for (int t = 0; t < 4; ++t) {
                uint* o = (uint*)&ax[t];
                const uint* ua = (const uint*)&av[t];
                const uint* ub = (const uint*)&bv[t];
#pragma unroll
                for (int jj = 0; jj < 4; ++jj) o[jj] = prodpk(ua[jj], ub[jj]);
            }
        }

        // ---- layer 1: h1 = relu(x@Wr^T + mean@Wl^T + bl) -> ab ----
#pragma unroll
        for (int c = 0; c < 8; ++c) {
            f32x4 acc = {0.f, 0.f, 0.f, 0.f};
            int brow = c * 16 + arow;
            int sw = (brow & 7) << 4;
#pragma unroll
            for (int t = 0; t < 4; ++t) {
                s16x8 br = *(const s16x8*)(smem + LOFF_WR + brow * 256 + ((t * 64 + agrp * 16) ^ sw));
                acc = __builtin_amdgcn_mfma_f32_16x16x32_bf16(ax[t], br, acc, 0, 0, 0);
            }
            if (low) {
#pragma unroll
                for (int t = 0; t < 4; ++t) {
                    s16x8 bw = *(const s16x8*)(smem + LOFF_WL + brow * 256 + ((t * 64 + agrp * 16) ^ sw));
                    acc = __builtin_amdgcn_mfma_f32_16x16x32_bf16(am[t], bw, acc, 0, 0, 0);
                }
            }
            float bias = *(const float*)(smem + LOFF_BL + brow * 4);
            uint p01 = cvtpk(fmaxf(acc[0] + bias, 0.f), fmaxf(acc[1] + bias, 0.f));
            uint p23 = cvtpk(fmaxf(acc[2] + bias, 0.f), fmaxf(acc[3] + bias, 0.f));
            int r0 = agrp * 4;
            *(ushort*)(ab + (r0 + 0) * 256 + ((2 * brow) ^ (((r0 + 0) & 7) << 4))) = (ushort)p01;
            *(ushort*)(ab + (r0 + 1) * 256 + ((2 * brow) ^ (((r0 + 1) & 7) << 4))) = (ushort)(p01 >> 16);
            *(ushort*)(ab + (r0 + 2) * 256 + ((2 * brow) ^ (((r0 + 2) & 7) << 4))) = (ushort)p23;
            *(ushort*)(ab + (r0 + 3) * 256 + ((2 * brow) ^ (((r0 + 3) & 7) << 4))) = (ushort)(p23 >> 16);
        }

        // ---- layer 2: h2 = relu(h1@W1^T + b1) ----
        s16x8 ah[4];
#pragma unroll
        for (int t = 0; t < 4; ++t)
            ah[t] = *(const s16x8*)(ab + arow * 256 + ((t * 64 + agrp * 16) ^ ((arow & 7) << 4)));
#pragma unroll
        for (int c = 0; c < 4; ++c) {
            f32x4 acc = {0.f, 0.f, 0.f, 0.f};
            int brow = c * 16 + arow;
            int sw = (brow & 7) << 4;
#pragma unroll
            for (int t = 0; t < 4; ++t) {
                s16x8 bw = *(const s16x8*)(smem + LOFF_W1 + brow * 256 + ((t * 64 + agrp * 16) ^ sw));
                acc = __builtin_amdgcn_mfma_f32_16x16x32_bf16(ah[t], bw, acc, 0, 0, 0);
            }
            float bias = *(const float*)(smem + LOFF_B1 + brow * 4);
            uint p01 = cvtpk(fmaxf(acc[0] + bias, 0.f), fmaxf(acc[1] + bias, 0.f));
            uint p23 = cvtpk(fmaxf(acc[2] + bias, 0.f), fmaxf(acc[3] + bias, 0.f));
            int r0 = agrp * 4;
            *(ushort*)(ab + (r0 + 0) * 256 + ((2 * brow) ^ (((r0 + 0) & 7) << 4))) = (ushort)p01;
            *(ushort*)(ab + (r0 + 1) * 256 + ((2 * brow) ^ (((r0 + 1) & 7) << 4))) = (ushort)(p01 >> 16);
            *(ushort*)(ab + (r0 + 2) * 256 + ((2 * brow) ^ (((r0 + 2) & 7) << 4))) = (ushort)p23;
            *(ushort*)(ab + (r0 + 3) * 256 + ((2 * brow) ^ (((r0 + 3) & 7) << 4))) = (ushort)(p23 >> 16);
        }

        // ---- layer 3: h3 = relu(h2@W2^T + b2) ----
        s16x8 a3[2];
#pragma unroll
        for (int t = 0; t < 2; ++t)
            a3[t] = *(const s16x8*)(ab + arow * 256 + ((t * 64 + agrp * 16) ^ ((arow & 7) << 4)));
#pragma unroll
        for (int c = 0; c < 2; ++c) {
            f32x4 acc = {0.f, 0.f, 0.f, 0.f};
            int brow = c * 16 + arow;
            int sw = (brow & 7) << 4;
#pragma unroll
            for (int t = 0; t < 2; ++t) {
                s16x8 bw = *(const s16x8*)(smem + LOFF_W2 + brow * 128 + ((t * 64 + agrp * 16) ^ sw));
                acc = __builtin_amdgcn_mfma_f32_16x16x32_bf16(a3[t], bw, acc, 0, 0, 0);
            }
            float bias = *(const float*)(smem + LOFF_B2 + brow * 4);
            uint p01 = cvtpk(fmaxf(acc[0] + bias, 0.f), fmaxf(acc[1] + bias, 0.f));
            uint p23 = cvtpk(fmaxf(acc[2] + bias, 0.f), fmaxf(acc[3] + bias, 0.f));
            int r0 = agrp * 4;
            *(ushort*)(ab + (r0 + 0) * 256 + ((2 * brow) ^ (((r0 + 0) & 7) << 4))) = (ushort)p01;
            *(ushort*)(ab + (r0 + 1) * 256 + ((2 * brow) ^ (((r0 + 1) & 7) << 4))) = (ushort)(p01 >> 16);
            *(ushort*)(ab + (r0 + 2) * 256 + ((2 * brow) ^ (((r0 + 2) & 7) << 4))) = (ushort)p23;
            *(ushort*)(ab + (r0 + 3) * 256 + ((2 * brow) ^ (((r0 + 3) & 7) << 4))) = (ushort)(p23 >> 16);
        }

        // ---- layer 4 + log_softmax: 4 lanes per edge + shfl reduce ----
        {
            s16x8 h = *(const s16x8*)(ab + arow * 256 + ((agrp * 16) ^ ((arow & 7) << 4)));
            float l0 = 0.f, l1 = 0.f;
#pragma unroll
            for (int jj = 0; jj < 8; ++jj) {
                float f = bf2f((ushort)h[jj]);
                l0 += f * W3s[agrp * 8 + jj];
                l1 += f * W3s[32 + agrp * 8 + jj];
            }
            l0 += __shfl_xor(l0, 16); l0 += __shfl_xor(l0, 32);
            l1 += __shfl_xor(l1, 16); l1 += __shfl_xor(l1, 32);
            if (agrp == 0) {
                l0 += B3s[0]; l1 += B3s[1];
                float m = fmaxf(l0, l1);
                float lse = m + __logf(__expf(l0 - m) + __expf(l1 - m));
                float2 p = { l0 - lse, l1 - lse };
                *(float2*)(out + (size_t)(eb + arow) * 2) = p;
            }
        }
    }
}

extern "C" void kernel_launch(void* const* d_in, const int* in_sizes, int n_in,
                              void* d_out, int out_size, void* d_ws, size_t ws_size,
                              hipStream_t stream) {
    const float* rna  = (const float*)d_in[0];
    const float* prot = (const float*)d_in[1];
    const int*   ei   = (const int*)d_in[2];
    const float* Wl   = (const float*)d_in[3];
    const float* bl   = (const float*)d_in[4];
    const float* Wr   = (const float*)d_in[5];
    const float* W1   = (const float*)d_in[6];
    const float* b1   = (const float*)d_in[7];
    const float* W2   = (const float*)d_in[8];
    const float* b2   = (const float*)d_in[9];
    const float* W3   = (const float*)d_in[10];
    const float* b3   = (const float*)d_in[11];
    float* out = (float*)d_out;

    char* ws = (char*)d_ws;
    ushort* nfbf   = (ushort*)(ws);                  // 25,600,000 B
    ushort* xlow   = (ushort*)(ws + 25600000);       // 25,600,000 B
    ushort* meanbf = (ushort*)(ws + 51200000);       // 25,600,000 B
    int*    cnt_i  = (int*)   (ws + 76800000);       //    400,000 B
    int*    offs   = (int*)   (ws + 77200000);       //    400,000 B
    int*    wptr   = (int*)   (ws + 77600000);       //    400,000 B
    int*    elist  = (int*)   (ws + 78000000);       //  3,200,000 B
    int*    bsum   = (int*)   (ws + 81200000);       //      1,024 B (256 ints)
    int*    flags  = (int*)   (ws + 81201024);       //         64 B
    char*   wimg   =          (ws + 81204096);       //     87,184 B

    // zero cnt_i .. flags (offs/wptr/elist/bsum get fully rewritten anyway)
    hipMemsetAsync(cnt_i, 0, 4401152, stream);
    k_pre1<<<15668, 256, 0, stream>>>(rna, prot, nfbf, ei, cnt_i,
                                      Wl, Wr, W1, W2, bl, b1, b2, W3, b3, wimg);
    hipFuncSetAttribute((const void*)k_mega, hipFuncAttributeMaxDynamicSharedMemorySize, LDS_TOTAL);
    k_mega<<<GRID, 1024, LDS_TOTAL, stream>>>(ei, nfbf, xlow, meanbf, cnt_i, offs,
                                              wptr, elist, bsum, flags, wimg, out);
}

// Round 8
// 263.551 us; speedup vs baseline: 3.7608x; 3.7608x over previous
//
#include <hip/hip_runtime.h>
#include <hip/hip_bf16.h>

#define N_NODE  100000
#define N_EDGE  800000
#define FEATD   128
#define NTILES  3125          /* 800000 / 256 edges per block-tile */
#define MLP_GRID 256

typedef float  f32x4 __attribute__((ext_vector_type(4)));
typedef short  s16x8 __attribute__((ext_vector_type(8)));

static __device__ __forceinline__ float bf2f(ushort h) {
    union { uint u; float f; } v; v.u = ((uint)h) << 16; return v.f;
}
static __device__ __forceinline__ ushort f2bf(float f) {
    union { float f; uint u; } v; v.f = f;
    uint u = v.u;
    u = u + 0x7FFFu + ((u >> 16) & 1u);   // RNE
    return (ushort)(u >> 16);
}
// pack 2 f32 -> 2 bf16 in one inst (no builtin on gfx950; RNE)
static __device__ __forceinline__ uint cvtpk(float lo, float hi) {
    uint r;
    asm("v_cvt_pk_bf16_f32 %0, %1, %2" : "=v"(r) : "v"(lo), "v"(hi));
    return r;
}
// elementwise product of 2 packed-bf16 pairs -> packed-bf16 pair (7 VALU)
static __device__ __forceinline__ uint prodpk(uint ua, uint ub) {
    union { uint u; float f; } al, ah, bl, bh;
    al.u = ua << 16; ah.u = ua & 0xFFFF0000u;
    bl.u = ub << 16; bh.u = ub & 0xFFFF0000u;
    return cvtpk(al.f * bl.f, ah.f * bh.f);
}
static __device__ __forceinline__ float lof(uint u) {
    union { uint u; float f; } v; v.u = u << 16; return v.f;
}
static __device__ __forceinline__ float hif(uint u) {
    union { uint u; float f; } v; v.u = u & 0xFFFF0000u; return v.f;
}

// LDS / weight-image layout (bytes), weights XOR-swizzled: byte ^= (row&7)<<4
#define LOFF_WL   0           /* 128 rows x 256B bf16 */
#define LOFF_WR   32768
#define LOFF_W1   65536       /* 64 rows x 256B */
#define LOFF_W2   81920       /* 32 rows x 128B */
#define LOFF_BL   86016
#define LOFF_B1   86528
#define LOFF_B2   86784
#define LOFF_W3   86912       /* 64 f32: W3[2][32] */
#define LOFF_B3   87168
#define IMG_BYTES 87184
#define LOFF_ABUF 87184       /* 16 waves x 4096B: [16 rows][256B] transpose buf */
#define LDS_TOTAL (LOFF_ABUF + 16 * 4096)   /* 152720 */

// ---------------- K_pre1: n_fea f32->bf16 + dst histogram + weight image ----
__global__ void k_pre1(const float* __restrict__ rna, const float* __restrict__ prot,
                       ushort* __restrict__ nfbf, const int* __restrict__ ei,
                       int* __restrict__ cnt_i,
                       const float* __restrict__ Wl, const float* __restrict__ Wr,
                       const float* __restrict__ W1, const float* __restrict__ W2,
                       const float* __restrict__ bl, const float* __restrict__ b1,
                       const float* __restrict__ b2, const float* __restrict__ W3,
                       const float* __restrict__ b3, char* __restrict__ wimg) {
    int b = blockIdx.x;
    if (b < 12500) {
        int i = (b * 256 + threadIdx.x) * 4;
        const float* src = (i < 50000 * FEATD) ? (rna + i) : (prot + (i - 50000 * FEATD));
        float4 v = *(const float4*)src;
        ushort4 o;
        o.x = f2bf(v.x); o.y = f2bf(v.y); o.z = f2bf(v.z); o.w = f2bf(v.w);
        *(ushort4*)(nfbf + i) = o;
    } else if (b < 15625) {
        int e = (b - 12500) * 256 + threadIdx.x;
        atomicAdd(&cnt_i[ei[N_EDGE + e]], 1);
    } else if (b < 15667) {
        // weights -> swizzled bf16 image (42 blocks x 1024 elems)
        int base = (b - 15625) * 1024 + threadIdx.x * 4;
#pragma unroll
        for (int q = 0; q < 4; ++q) {
            int i = base + q;
            if (i < 16384) {
                int row = i >> 7, col = i & 127;
                *(ushort*)(wimg + LOFF_WL + row * 256 + ((2 * col) ^ ((row & 7) << 4))) = f2bf(Wl[i]);
            } else if (i < 32768) {
                int j = i - 16384, row = j >> 7, col = j & 127;
                *(ushort*)(wimg + LOFF_WR + row * 256 + ((2 * col) ^ ((row & 7) << 4))) = f2bf(Wr[j]);
            } else if (i < 40960) {
                int j = i - 32768, row = j >> 7, col = j & 127;
                *(ushort*)(wimg + LOFF_W1 + row * 256 + ((2 * col) ^ ((row & 7) << 4))) = f2bf(W1[j]);
            } else if (i < 43008) {
                int j = i - 40960, row = j >> 6, col = j & 63;
                *(ushort*)(wimg + LOFF_W2 + row * 128 + ((2 * col) ^ ((row & 7) << 4))) = f2bf(W2[j]);
            }
        }
    } else {
        // biases + W3/b3: 256-thread block, threads 0..65 do TWO writes
        int t = threadIdx.x;
        if (t < 128)      *(float*)(wimg + LOFF_BL + t * 4) = bl[t];
        else if (t < 192) *(float*)(wimg + LOFF_B1 + (t - 128) * 4) = b1[t - 128];
        else if (t < 224) *(float*)(wimg + LOFF_B2 + (t - 192) * 4) = b2[t - 192];
        if (t < 64)       *(float*)(wimg + LOFF_W3 + t * 4) = W3[t];
        else if (t < 66)  *(float*)(wimg + LOFF_B3 + (t - 64) * 4) = b3[t - 64];
    }
}

// ---------------- K3c: per-block sums of cnt_i ----------------
__global__ void k_blocksum(const int* __restrict__ cnt_i, int* __restrict__ bsum) {
    __shared__ int sh[256];
    int i = blockIdx.x * 256 + threadIdx.x;
    sh[threadIdx.x] = (i < N_NODE) ? cnt_i[i] : 0;
    __syncthreads();
    for (int o = 128; o > 0; o >>= 1) {
        if (threadIdx.x < o) sh[threadIdx.x] += sh[threadIdx.x + o];
        __syncthreads();
    }
    if (threadIdx.x == 0) bsum[blockIdx.x] = sh[0];
}

// ------- K3e': local scan + inline redundant scan of 391 block sums ----------
__global__ void k_scanlocal2(const int* __restrict__ cnt_i, const int* __restrict__ bsum,
                             int* __restrict__ offs, int* __restrict__ wptr) {
    __shared__ int sh[256];
    __shared__ int sb[512];
    int tid = threadIdx.x;
    int i = blockIdx.x * 256 + tid;
    int v = (i < N_NODE) ? cnt_i[i] : 0;
    sh[tid] = v;
    sb[tid]       = (tid < 391)       ? bsum[tid]       : 0;
    sb[256 + tid] = (256 + tid < 391) ? bsum[256 + tid] : 0;
    __syncthreads();
    // Hillis-Steele on 512 (2 elems/thread) and on 256 concurrently
    for (int o = 1; o < 512; o <<= 1) {
        int t0 = (tid >= o) ? sb[tid - o] : 0;
        int t1 = (256 + tid >= o) ? sb[256 + tid - o] : 0;
        int t2 = (o < 256 && tid >= o) ? sh[tid - o] : 0;
        __syncthreads();
        sb[tid] += t0;
        sb[256 + tid] += t1;
        if (o < 256) sh[tid] += t2;
        __syncthreads();
    }
    if (i < N_NODE) {
        int bbase = (blockIdx.x == 0) ? 0 : sb[blockIdx.x - 1];
        int excl = sh[tid] - v + bbase;
        offs[i] = excl;
        wptr[i] = excl;
    }
}

// ---------------- K_pre2: xlow (2-row ILP) + CSR fill (fused) ----------------
__global__ void k_pre2(const int* __restrict__ ei, const ushort* __restrict__ nfbf,
                       ushort* __restrict__ xlow, int* __restrict__ wptr,
                       int* __restrict__ elist) {
    int b = blockIdx.x;
    if (b < 12500) {
        int w = threadIdx.x >> 6, lane = threadIdx.x & 63;
        int s = b * 8 + w * 2;          // rows s, s+1
        int a0 = ei[s],     d0 = ei[N_EDGE + s];
        int a1 = ei[s + 1], d1 = ei[N_EDGE + s + 1];
        uint ua0 = *(const uint*)(nfbf + (size_t)a0 * FEATD + lane * 2);
        uint ub0 = *(const uint*)(nfbf + (size_t)d0 * FEATD + lane * 2);
        uint ua1 = *(const uint*)(nfbf + (size_t)a1 * FEATD + lane * 2);
        uint ub1 = *(const uint*)(nfbf + (size_t)d1 * FEATD + lane * 2);
        *(uint*)(xlow + (size_t)s * FEATD + lane * 2)       = prodpk(ua0, ub0);
        *(uint*)(xlow + (size_t)(s + 1) * FEATD + lane * 2) = prodpk(ua1, ub1);
    } else {
        int e = (b - 12500) * 256 + threadIdx.x;
        int d = ei[N_EDGE + e];
        int s = ei[e];
        int pos = atomicAdd(&wptr[d], 1);
        elist[pos] = s;
    }
}

// ---------------- K3g: gather aggregation, 8 gathers in flight ---------------
__global__ __launch_bounds__(256) void k_agg(
        const int* __restrict__ cnt_i, const int* __restrict__ offs,
        const int* __restrict__ elist, const ushort* __restrict__ xlow,
        ushort* __restrict__ meanbf) {
    int t = blockIdx.x * 256 + threadIdx.x;
    int d = t >> 6, lane = t & 63;
    if (d >= N_NODE) return;
    int c = cnt_i[d], base = offs[d];
    int half = lane >> 5, l32 = lane & 31;
    float a0 = 0.f, a1 = 0.f, a2 = 0.f, a3 = 0.f;
    int k = half;
    // 4-way unroll over this half's stride-2 sequence: 4 gathers in flight/half
    for (; k + 6 < c; k += 8) {
        int s0 = elist[base + k];
        int s1 = elist[base + k + 2];
        int s2 = elist[base + k + 4];
        int s3 = elist[base + k + 6];
        uint2 u0 = *(const uint2*)(xlow + (size_t)s0 * FEATD + l32 * 4);
        uint2 u1 = *(const uint2*)(xlow + (size_t)s1 * FEATD + l32 * 4);
        uint2 u2 = *(const uint2*)(xlow + (size_t)s2 * FEATD + l32 * 4);
        uint2 u3 = *(const uint2*)(xlow + (size_t)s3 * FEATD + l32 * 4);
        a0 += lof(u0.x) + lof(u1.x) + lof(u2.x) + lof(u3.x);
        a1 += hif(u0.x) + hif(u1.x) + hif(u2.x) + hif(u3.x);
        a2 += lof(u0.y) + lof(u1.y) + lof(u2.y) + lof(u3.y);
        a3 += hif(u0.y) + hif(u1.y) + hif(u2.y) + hif(u3.y);
    }
    for (; k + 2 < c; k += 4) {
        int s0 = elist[base + k];
        int s1 = elist[base + k + 2];
        uint2 u0 = *(const uint2*)(xlow + (size_t)s0 * FEATD + l32 * 4);
        uint2 u1 = *(const uint2*)(xlow + (size_t)s1 * FEATD + l32 * 4);
        a0 += lof(u0.x) + lof(u1.x); a1 += hif(u0.x) + hif(u1.x);
        a2 += lof(u0.y) + lof(u1.y); a3 += hif(u0.y) + hif(u1.y);
    }
    for (; k < c; k += 2) {
        int s = elist[base + k];
        uint2 u = *(const uint2*)(xlow + (size_t)s * FEATD + l32 * 4);
        a0 += lof(u.x); a1 += hif(u.x); a2 += lof(u.y); a3 += hif(u.y);
    }
    a0 += __shfl_xor(a0, 32); a1 += __shfl_xor(a1, 32);
    a2 += __shfl_xor(a2, 32); a3 += __shfl_xor(a3, 32);
    if (half == 0) {
        float sc = 1.0f / fmaxf((float)c, 1.0f);
        uint2 o;
        o.x = cvtpk(a0 * sc, a1 * sc);
        o.y = cvtpk(a2 * sc, a3 * sc);
        *(uint2*)(meanbf + (size_t)d * FEATD + l32 * 4) = o;
    }
}

// ---------------- K4: persistent fused MLP + log_softmax + labels ------------
__global__ __launch_bounds__(1024, 4) void k_mlp(
        const int* __restrict__ ei, const ushort* __restrict__ nfbf,
        const ushort* __restrict__ xlow, const ushort* __restrict__ meanbf,
        const char* __restrict__ wimg, float* __restrict__ out)
{
    extern __shared__ char smem[];
    const int tid = threadIdx.x;

    // ---- labels (coalesced, one float4 per thread) ----
    {
        int g = blockIdx.x * 1024 + tid;
        if (g < N_EDGE / 4) {
            float val = (g * 4 < N_EDGE / 2) ? 1.0f : 0.0f;   // 400000 % 4 == 0
            float4 v = { val, val, val, val };
            *(float4*)(out + 2 * (size_t)N_EDGE + g * 4) = v;
        }
    }

    // ---- stage pre-built weight image (straight copy) ----
    {
        const uint4* src = (const uint4*)wimg;
        uint4* dst = (uint4*)smem;
        for (int i = tid; i < IMG_BYTES / 16; i += 1024) dst[i] = src[i];
    }
    __syncthreads();

    const int w = tid >> 6, lane = tid & 63;
    const int arow = lane & 15, agrp = lane >> 4;
    char* ab = smem + LOFF_ABUF + w * 4096;
    const float* W3s = (const float*)(smem + LOFF_W3);
    const float* B3s = (const float*)(smem + LOFF_B3);

    for (int tile = blockIdx.x; tile < NTILES; tile += MLP_GRID) {
        const int eb = tile * 256 + w * 16;          // this wave's 16 edges
        const bool low = (eb < N_NODE);              // 16-aligned boundary: exact

        // ---- build layer-1 A fragments directly in registers ----
        s16x8 ax[4], am[4];
        if (low) {
            const ushort* xr = xlow   + (size_t)(eb + arow) * FEATD + agrp * 8;
            const ushort* mr = meanbf + (size_t)(eb + arow) * FEATD + agrp * 8;
#pragma unroll
            for (int t = 0; t < 4; ++t) {
                ax[t] = *(const s16x8*)(xr + t * 32);
                am[t] = *(const s16x8*)(mr + t * 32);
            }
        } else {
            int e = eb + arow;
            int s = ei[e], d = ei[N_EDGE + e];
            const ushort* sr = nfbf + (size_t)s * FEATD + agrp * 8;
            const ushort* dr = nfbf + (size_t)d * FEATD + agrp * 8;
            s16x8 av[4], bv[4];
#pragma unroll
            for (int t = 0; t < 4; ++t) {
                av[t] = *(const s16x8*)(sr + t * 32);
                bv[t] = *(const s16x8*)(dr + t * 32);
            }
#pragma unroll
            for (int t = 0; t < 4; ++t) {
                uint* o = (uint*)&ax[t];
                const uint* ua = (const uint*)&av[t];
                const uint* ub = (const uint*)&bv[t];
#pragma unroll
                for (int j = 0; j < 4; ++j) o[j] = prodpk(ua[j], ub[j]);
            }
        }

        // ---- layer 1: h1 = relu(x@Wr^T + mean@Wl^T + bl) -> ab ----
#pragma unroll
        for (int c = 0; c < 8; ++c) {
            f32x4 acc = {0.f, 0.f, 0.f, 0.f};
            int brow = c * 16 + arow;
            int sw = (brow & 7) << 4;
#pragma unroll
            for (int t = 0; t < 4; ++t) {
                s16x8 br = *(const s16x8*)(smem + LOFF_WR + brow * 256 + ((t * 64 + agrp * 16) ^ sw));
                acc = __builtin_amdgcn_mfma_f32_16x16x32_bf16(ax[t], br, acc, 0, 0, 0);
            }
            if (low) {
#pragma unroll
                for (int t = 0; t < 4; ++t) {
                    s16x8 bw = *(const s16x8*)(smem + LOFF_WL + brow * 256 + ((t * 64 + agrp * 16) ^ sw));
                    acc = __builtin_amdgcn_mfma_f32_16x16x32_bf16(am[t], bw, acc, 0, 0, 0);
                }
            }
            float bias = *(const float*)(smem + LOFF_BL + brow * 4);
            uint p01 = cvtpk(fmaxf(acc[0] + bias, 0.f), fmaxf(acc[1] + bias, 0.f));
            uint p23 = cvtpk(fmaxf(acc[2] + bias, 0.f), fmaxf(acc[3] + bias, 0.f));
            int r0 = agrp * 4;
            *(ushort*)(ab + (r0 + 0) * 256 + ((2 * brow) ^ (((r0 + 0) & 7) << 4))) = (ushort)p01;
            *(ushort*)(ab + (r0 + 1) * 256 + ((2 * brow) ^ (((r0 + 1) & 7) << 4))) = (ushort)(p01 >> 16);
            *(ushort*)(ab + (r0 + 2) * 256 + ((2 * brow) ^ (((r0 + 2) & 7) << 4))) = (ushort)p23;
            *(ushort*)(ab + (r0 + 3) * 256 + ((2 * brow) ^ (((r0 + 3) & 7) << 4))) = (ushort)(p23 >> 16);
        }

        // ---- layer 2: h2 = relu(h1@W1^T + b1) ----
        s16x8 ah[4];
#pragma unroll
        for (int t = 0; t < 4; ++t)
            ah[t] = *(const s16x8*)(ab + arow * 256 + ((t * 64 + agrp * 16) ^ ((arow & 7) << 4)));
#pragma unroll
        for (int c = 0; c < 4; ++c) {
            f32x4 acc = {0.f, 0.f, 0.f, 0.f};
            int brow = c * 16 + arow;
            int sw = (brow & 7) << 4;
#pragma unroll
            for (int t = 0; t < 4; ++t) {
                s16x8 bw = *(const s16x8*)(smem + LOFF_W1 + brow * 256 + ((t * 64 + agrp * 16) ^ sw));
                acc = __builtin_amdgcn_mfma_f32_16x16x32_bf16(ah[t], bw, acc, 0, 0, 0);
            }
            float bias = *(const float*)(smem + LOFF_B1 + brow * 4);
            uint p01 = cvtpk(fmaxf(acc[0] + bias, 0.f), fmaxf(acc[1] + bias, 0.f));
            uint p23 = cvtpk(fmaxf(acc[2] + bias, 0.f), fmaxf(acc[3] + bias, 0.f));
            int r0 = agrp * 4;
            *(ushort*)(ab + (r0 + 0) * 256 + ((2 * brow) ^ (((r0 + 0) & 7) << 4))) = (ushort)p01;
            *(ushort*)(ab + (r0 + 1) * 256 + ((2 * brow) ^ (((r0 + 1) & 7) << 4))) = (ushort)(p01 >> 16);
            *(ushort*)(ab + (r0 + 2) * 256 + ((2 * brow) ^ (((r0 + 2) & 7) << 4))) = (ushort)p23;
            *(ushort*)(ab + (r0 + 3) * 256 + ((2 * brow) ^ (((r0 + 3) & 7) << 4))) = (ushort)(p23 >> 16);
        }

        // ---- layer 3: h3 = relu(h2@W2^T + b2) ----
        s16x8 a3[2];
#pragma unroll
        for (int t = 0; t < 2; ++t)
            a3[t] = *(const s16x8*)(ab + arow * 256 + ((t * 64 + agrp * 16) ^ ((arow & 7) << 4)));
#pragma unroll
        for (int c = 0; c < 2; ++c) {
            f32x4 acc = {0.f, 0.f, 0.f, 0.f};
            int brow = c * 16 + arow;
            int sw = (brow & 7) << 4;
#pragma unroll
            for (int t = 0; t < 2; ++t) {
                s16x8 bw = *(const s16x8*)(smem + LOFF_W2 + brow * 128 + ((t * 64 + agrp * 16) ^ sw));
                acc = __builtin_amdgcn_mfma_f32_16x16x32_bf16(a3[t], bw, acc, 0, 0, 0);
            }
            float bias = *(const float*)(smem + LOFF_B2 + brow * 4);
            uint p01 = cvtpk(fmaxf(acc[0] + bias, 0.f), fmaxf(acc[1] + bias, 0.f));
            uint p23 = cvtpk(fmaxf(acc[2] + bias, 0.f), fmaxf(acc[3] + bias, 0.f));
            int r0 = agrp * 4;
            *(ushort*)(ab + (r0 + 0) * 256 + ((2 * brow) ^ (((r0 + 0) & 7) << 4))) = (ushort)p01;
            *(ushort*)(ab + (r0 + 1) * 256 + ((2 * brow) ^ (((r0 + 1) & 7) << 4))) = (ushort)(p01 >> 16);
            *(ushort*)(ab + (r0 + 2) * 256 + ((2 * brow) ^ (((r0 + 2) & 7) << 4))) = (ushort)p23;
            *(ushort*)(ab + (r0 + 3) * 256 + ((2 * brow) ^ (((r0 + 3) & 7) << 4))) = (ushort)(p23 >> 16);
        }

        // ---- layer 4 + log_softmax: 4 lanes per edge + shfl reduce ----
        {
            s16x8 h = *(const s16x8*)(ab + arow * 256 + ((agrp * 16) ^ ((arow & 7) << 4)));
            float l0 = 0.f, l1 = 0.f;
#pragma unroll
            for (int j = 0; j < 8; ++j) {
                float f = bf2f((ushort)h[j]);
                l0 += f * W3s[agrp * 8 + j];
                l1 += f * W3s[32 + agrp * 8 + j];
            }
            l0 += __shfl_xor(l0, 16); l0 += __shfl_xor(l0, 32);
            l1 += __shfl_xor(l1, 16); l1 += __shfl_xor(l1, 32);
            if (agrp == 0) {
                l0 += B3s[0]; l1 += B3s[1];
                float m = fmaxf(l0, l1);
                float lse = m + __logf(__expf(l0 - m) + __expf(l1 - m));
                float2 p = { l0 - lse, l1 - lse };
                *(float2*)(out + (size_t)(eb + arow) * 2) = p;
            }
        }
    }
}

extern "C" void kernel_launch(void* const* d_in, const int* in_sizes, int n_in,
                              void* d_out, int out_size, void* d_ws, size_t ws_size,
                              hipStream_t stream) {
    const float* rna  = (const float*)d_in[0];
    const float* prot = (const float*)d_in[1];
    const int*   ei   = (const int*)d_in[2];
    const float* Wl   = (const float*)d_in[3];
    const float* bl   = (const float*)d_in[4];
    const float* Wr   = (const float*)d_in[5];
    const float* W1   = (const float*)d_in[6];
    const float* b1   = (const float*)d_in[7];
    const float* W2   = (const float*)d_in[8];
    const float* b2   = (const float*)d_in[9];
    const float* W3   = (const float*)d_in[10];
    const float* b3   = (const float*)d_in[11];
    float* out = (float*)d_out;

    char* ws = (char*)d_ws;
    ushort* nfbf   = (ushort*)(ws);                  // 25,600,000 B
    ushort* xlow   = (ushort*)(ws + 25600000);       // 25,600,000 B
    ushort* meanbf = (ushort*)(ws + 51200000);       // 25,600,000 B
    int*    cnt_i  = (int*)   (ws + 76800000);       //    400,000 B
    int*    offs   = (int*)   (ws + 77200000);       //    400,000 B
    int*    wptr   = (int*)   (ws + 77600000);       //    400,000 B
    int*    elist  = (int*)   (ws + 78000000);       //  3,200,000 B
    int*    bsum   = (int*)   (ws + 81200000);       //      2,048 B
    char*   wimg   =          (ws + 81204096);       //     87,184 B

    hipMemsetAsync(cnt_i, 0, 400000, stream);
    k_pre1<<<15668, 256, 0, stream>>>(rna, prot, nfbf, ei, cnt_i,
                                      Wl, Wr, W1, W2, bl, b1, b2, W3, b3, wimg);
    k_blocksum<<<391, 256, 0, stream>>>(cnt_i, bsum);
    k_scanlocal2<<<391, 256, 0, stream>>>(cnt_i, bsum, offs, wptr);
    k_pre2<<<15625, 256, 0, stream>>>(ei, nfbf, xlow, wptr, elist);
    k_agg<<<25000, 256, 0, stream>>>(cnt_i, offs, elist, xlow, meanbf);
    hipFuncSetAttribute((const void*)k_mlp, hipFuncAttributeMaxDynamicSharedMemorySize, LDS_TOTAL);
    k_mlp<<<MLP_GRID, 1024, LDS_TOTAL, stream>>>(ei, nfbf, xlow, meanbf, wimg, out);
}